// Round 1
// baseline (553.337 us; speedup 1.0000x reference)
//
#include <hip/hip_runtime.h>

typedef __bf16 bf16_t;
typedef __bf16 bf16x4 __attribute__((ext_vector_type(4)));
typedef __bf16 bf16x8 __attribute__((ext_vector_type(8)));
typedef float f32x4 __attribute__((ext_vector_type(4)));

#define NB 4        // batch
#define SS 2048     // seq
#define DM 1024     // d_model
#define NH 16       // heads
#define DK 64       // d_kv
#define MM (NB*SS)  // 8192 rows

// ---------------- convert H (fp32) -> bf16 ----------------
__global__ __launch_bounds__(256) void k_convert(const float* __restrict__ in,
                                                 bf16_t* __restrict__ out, int n4) {
  int i = blockIdx.x * 256 + threadIdx.x;
  if (i < n4) {
    float4 v = ((const float4*)in)[i];
    bf16x4 o = {(bf16_t)v.x, (bf16_t)v.y, (bf16_t)v.z, (bf16_t)v.w};
    *(bf16x4*)(out + 4 * (size_t)i) = o;
  }
}

// ---------------- transpose-convert weights: Wt[n][k] = bf16(W[k][n]) ----------------
__global__ __launch_bounds__(256) void k_transpose(
    const float* __restrict__ W0, const float* __restrict__ W1,
    const float* __restrict__ W2, const float* __restrict__ W3,
    bf16_t* __restrict__ T0, bf16_t* __restrict__ T1,
    bf16_t* __restrict__ T2, bf16_t* __restrict__ T3) {
  __shared__ float t[64][65];
  const float* W = blockIdx.z == 0 ? W0 : blockIdx.z == 1 ? W1 : blockIdx.z == 2 ? W2 : W3;
  bf16_t* T = blockIdx.z == 0 ? T0 : blockIdx.z == 1 ? T1 : blockIdx.z == 2 ? T2 : T3;
  int k0 = blockIdx.y * 64, n0 = blockIdx.x * 64;
  int tid = threadIdx.x;
#pragma unroll
  for (int i = 0; i < 16; i++) {
    int idx = tid + i * 256; int r = idx >> 6, c = idx & 63;
    t[r][c] = W[(size_t)(k0 + r) * DM + n0 + c];
  }
  __syncthreads();
#pragma unroll
  for (int i = 0; i < 16; i++) {
    int idx = tid + i * 256; int r = idx >> 6, c = idx & 63;
    T[(size_t)(n0 + r) * DM + k0 + c] = (bf16_t)t[c][r];
  }
}

// ---------------- T5 relative-position bias table: biasT[h][rel+2047] ----------------
__global__ __launch_bounds__(256) void k_bias(const float* __restrict__ rel_emb,
                                              float* __restrict__ biasT) {
  int t = blockIdx.x * 256 + threadIdx.x;
  if (t >= 2 * SS - 1) return;
  int rel = t - (SS - 1);      // rel = j - i (memory - context)
  int n = -rel;                // reference: n = -relative_position
  int ret = 0;
  if (n < 0) { ret = 16; n = -n; }
  int bucket;
  if (n < 8) bucket = n;
  else {
    int v = 8 + (int)(logf((float)n * 0.125f) * (8.0f / logf(16.0f)));
    bucket = v < 15 ? v : 15;
  }
  bucket += ret;
#pragma unroll
  for (int h = 0; h < NH; h++) biasT[h * (2 * SS - 1) + t] = rel_emb[bucket * NH + h];
}

// ---------------- shared GEMM mainloop: C[128x128] = A[M x K] * Bt[N x K]^T ----------------
// Fragment layouts (gfx950 mfma_f32_16x16x32_bf16, HW-verified):
//   A[m=lane&15][k=quad*8+j], B[n=lane&15][k=quad*8+j], D[row=quad*4+reg][col=lane&15]
#define LDP 40  // padded LDS row (elems) -> 80B rows, <=2-way bank aliasing (free)
__device__ __forceinline__ void gemm_tile(const bf16_t* __restrict__ A,
                                          const bf16_t* __restrict__ Bt, const int K,
                                          const int m0, const int n0,
                                          bf16_t* As, bf16_t* Bs, f32x4 (&acc)[4][4]) {
  const int tid = threadIdx.x;
  const int lane = tid & 63, wave = tid >> 6;
  const int l15 = lane & 15, quad = lane >> 4;
  const int wm = (wave >> 1) * 64, wn = (wave & 1) * 64;
  const f32x4 z4 = {0.f, 0.f, 0.f, 0.f};
#pragma unroll
  for (int i = 0; i < 4; i++)
#pragma unroll
    for (int j = 0; j < 4; j++) acc[i][j] = z4;

  const int r0 = tid >> 2;          // 0..63
  const int cc = (tid & 3) * 8;     // 0,8,16,24
  for (int k0 = 0; k0 < K; k0 += 32) {
    __syncthreads();
    bf16x8 a0 = *(const bf16x8*)(A + (size_t)(m0 + r0) * K + k0 + cc);
    bf16x8 a1 = *(const bf16x8*)(A + (size_t)(m0 + r0 + 64) * K + k0 + cc);
    bf16x8 b0 = *(const bf16x8*)(Bt + (size_t)(n0 + r0) * K + k0 + cc);
    bf16x8 b1 = *(const bf16x8*)(Bt + (size_t)(n0 + r0 + 64) * K + k0 + cc);
    *(bf16x8*)(As + r0 * LDP + cc) = a0;
    *(bf16x8*)(As + (r0 + 64) * LDP + cc) = a1;
    *(bf16x8*)(Bs + r0 * LDP + cc) = b0;
    *(bf16x8*)(Bs + (r0 + 64) * LDP + cc) = b1;
    __syncthreads();
    bf16x8 af[4], bfr[4];
#pragma unroll
    for (int i = 0; i < 4; i++) {
      af[i]  = *(const bf16x8*)(As + (wm + i * 16 + l15) * LDP + quad * 8);
      bfr[i] = *(const bf16x8*)(Bs + (wn + i * 16 + l15) * LDP + quad * 8);
    }
#pragma unroll
    for (int i = 0; i < 4; i++)
#pragma unroll
      for (int j = 0; j < 4; j++)
        acc[i][j] = __builtin_amdgcn_mfma_f32_16x16x32_bf16(af[i], bfr[j], acc[i][j], 0, 0, 0);
  }
}

// ---------------- QKV projection: writes Q,K [bh][s][d], V transposed [bh][d][s] ----------------
__global__ __launch_bounds__(256) void k_gemm_qkv(
    const bf16_t* __restrict__ A, const bf16_t* __restrict__ Wqt,
    const bf16_t* __restrict__ Wkt, const bf16_t* __restrict__ Wvt,
    bf16_t* __restrict__ Q, bf16_t* __restrict__ Ko, bf16_t* __restrict__ Vt) {
  __shared__ bf16_t As[128 * LDP];
  __shared__ bf16_t Bs[128 * LDP];
  const int which = blockIdx.z;
  const bf16_t* Bt = which == 0 ? Wqt : (which == 1 ? Wkt : Wvt);
  const int m0 = blockIdx.y * 128, n0 = blockIdx.x * 128;
  f32x4 acc[4][4];
  gemm_tile(A, Bt, DM, m0, n0, As, Bs, acc);

  const int tid = threadIdx.x;
  const int lane = tid & 63, wave = tid >> 6;
  const int l15 = lane & 15, quad = lane >> 4;
  const int wm = (wave >> 1) * 64, wn = (wave & 1) * 64;

  if (which < 2) {
    bf16_t* dst = which == 0 ? Q : Ko;
#pragma unroll
    for (int i = 0; i < 4; i++)
#pragma unroll
      for (int j = 0; j < 4; j++)
#pragma unroll
        for (int r = 0; r < 4; r++) {
          int m = m0 + wm + i * 16 + quad * 4 + r;
          int n = n0 + wn + j * 16 + l15;
          int b = m >> 11, s = m & (SS - 1);
          int h = n >> 6, d = n & 63;
          dst[(((size_t)(b * NH + h)) * SS + s) * DK + d] = (bf16_t)acc[i][j][r];
        }
  } else {
#pragma unroll
    for (int i = 0; i < 4; i++)
#pragma unroll
      for (int j = 0; j < 4; j++) {
        int m = m0 + wm + i * 16 + quad * 4;   // 4 consecutive s
        int n = n0 + wn + j * 16 + l15;
        int b = m >> 11, s = m & (SS - 1);
        int h = n >> 6, d = n & 63;
        bf16x4 pk = {(bf16_t)acc[i][j][0], (bf16_t)acc[i][j][1],
                     (bf16_t)acc[i][j][2], (bf16_t)acc[i][j][3]};
        *(bf16x4*)(&Vt[(((size_t)(b * NH + h)) * DK + d) * SS + s]) = pk;
      }
  }
}

// ---------------- flash attention: 128 Q-rows per block, one (b,h) ----------------
__global__ __launch_bounds__(256) void k_attn(const bf16_t* __restrict__ Qg,
                                              const bf16_t* __restrict__ Kg,
                                              const bf16_t* __restrict__ Vt,
                                              const float* __restrict__ biasT,
                                              bf16_t* __restrict__ ctx) {
  const int bh = blockIdx.y;
  const int b = bh >> 4, h = bh & 15;
  const int it0 = blockIdx.x * 128;
  const bf16_t* Qp = Qg + ((size_t)bh * SS + it0) * DK;
  const bf16_t* Kp = Kg + (size_t)bh * SS * DK;
  const bf16_t* Vp = Vt + (size_t)bh * DK * SS;
  const float* biasH = biasT + h * (2 * SS - 1);

  __shared__ bf16_t Qs[128][72];
  __shared__ bf16_t Ks[32][72];
  __shared__ bf16_t Vs[64][40];
  __shared__ bf16_t Ps[128][40];
  __shared__ float bias_s[160];

  const int tid = threadIdx.x;
  const int lane = tid & 63, wave = tid >> 6;
  const int l15 = lane & 15, quad = lane >> 4;

#pragma unroll
  for (int i = 0; i < 4; i++) {
    int c = tid + i * 256;
    int r = c >> 3, cc = (c & 7) * 8;
    *(bf16x8*)(&Qs[r][cc]) = *(const bf16x8*)(Qp + r * DK + cc);
  }
  __syncthreads();

  // Q fragments are loop-invariant: hoist out of the K-loop.
  bf16x8 qf0[2], qf1[2];
#pragma unroll
  for (int mi = 0; mi < 2; mi++) {
    int row = wave * 32 + mi * 16 + l15;
    qf0[mi] = *(const bf16x8*)(&Qs[row][quad * 8]);
    qf1[mi] = *(const bf16x8*)(&Qs[row][32 + quad * 8]);
  }

  float mrow[2][4], lrow[2][4], arow[2][4];
  f32x4 accO[2][4];
  const f32x4 z4 = {0.f, 0.f, 0.f, 0.f};
#pragma unroll
  for (int mi = 0; mi < 2; mi++)
#pragma unroll
    for (int r = 0; r < 4; r++) { mrow[mi][r] = -1e30f; lrow[mi][r] = 0.f; }
#pragma unroll
  for (int mi = 0; mi < 2; mi++)
#pragma unroll
    for (int ni = 0; ni < 4; ni++) accO[mi][ni] = z4;

  for (int j0 = 0; j0 < SS; j0 += 32) {
    __syncthreads();
    { int r = tid >> 3, cc = (tid & 7) * 8;
      *(bf16x8*)(&Ks[r][cc]) = *(const bf16x8*)(Kp + (size_t)(j0 + r) * DK + cc); }
    { int r = tid >> 2, cc = (tid & 3) * 8;
      *(bf16x8*)(&Vs[r][cc]) = *(const bf16x8*)(Vp + (size_t)r * SS + j0 + cc); }
    if (tid < 159) bias_s[tid] = biasH[j0 - it0 - 127 + tid + (SS - 1)];
    __syncthreads();

    // scores = Q K^T  (rows: wave*32+mi*16, cols: ji*16; K dim = d = 64 -> 2 MFMAs)
    f32x4 sc[2][2];
    bf16x8 kf0[2], kf1[2];
#pragma unroll
    for (int ji = 0; ji < 2; ji++) {
      int row = ji * 16 + l15;
      kf0[ji] = *(const bf16x8*)(&Ks[row][quad * 8]);
      kf1[ji] = *(const bf16x8*)(&Ks[row][32 + quad * 8]);
    }
#pragma unroll
    for (int mi = 0; mi < 2; mi++)
#pragma unroll
      for (int ji = 0; ji < 2; ji++) {
        f32x4 t = __builtin_amdgcn_mfma_f32_16x16x32_bf16(qf0[mi], kf0[ji], z4, 0, 0, 0);
        sc[mi][ji] = __builtin_amdgcn_mfma_f32_16x16x32_bf16(qf1[mi], kf1[ji], t, 0, 0, 0);
      }

    // online softmax (per row; 16 lanes of a quad share a row -> xor-shuffle reduce)
#pragma unroll
    for (int mi = 0; mi < 2; mi++) {
#pragma unroll
      for (int r = 0; r < 4; r++) {
        int i_loc = wave * 32 + mi * 16 + quad * 4 + r;
        float s0 = sc[mi][0][r] + bias_s[l15 - i_loc + 127];
        float s1 = sc[mi][1][r] + bias_s[16 + l15 - i_loc + 127];
        float v = fmaxf(s0, s1);
        v = fmaxf(v, __shfl_xor(v, 1));
        v = fmaxf(v, __shfl_xor(v, 2));
        v = fmaxf(v, __shfl_xor(v, 4));
        v = fmaxf(v, __shfl_xor(v, 8));
        float mnew = fmaxf(mrow[mi][r], v);
        float alpha = __expf(mrow[mi][r] - mnew);
        mrow[mi][r] = mnew;
        float p0 = __expf(s0 - mnew);
        float p1 = __expf(s1 - mnew);
        float rs = p0 + p1;
        rs += __shfl_xor(rs, 1);
        rs += __shfl_xor(rs, 2);
        rs += __shfl_xor(rs, 4);
        rs += __shfl_xor(rs, 8);
        lrow[mi][r] = lrow[mi][r] * alpha + rs;
        arow[mi][r] = alpha;
        Ps[i_loc][l15] = (bf16_t)p0;
        Ps[i_loc][16 + l15] = (bf16_t)p1;
      }
    }

    // PV: P is A-operand (round-trip via Ps, per-wave-private rows), V^T gives contiguous B-frags
    bf16x8 pf[2], vf[4];
#pragma unroll
    for (int mi = 0; mi < 2; mi++)
      pf[mi] = *(const bf16x8*)(&Ps[wave * 32 + mi * 16 + l15][quad * 8]);
#pragma unroll
    for (int ni = 0; ni < 4; ni++)
      vf[ni] = *(const bf16x8*)(&Vs[ni * 16 + l15][quad * 8]);
#pragma unroll
    for (int mi = 0; mi < 2; mi++)
#pragma unroll
      for (int ni = 0; ni < 4; ni++) {
        f32x4 t = accO[mi][ni];
#pragma unroll
        for (int r = 0; r < 4; r++) t[r] *= arow[mi][r];
        accO[mi][ni] = __builtin_amdgcn_mfma_f32_16x16x32_bf16(pf[mi], vf[ni], t, 0, 0, 0);
      }
  }

  // epilogue: normalize, write ctx[b][s][h*64+d] as bf16
#pragma unroll
  for (int mi = 0; mi < 2; mi++) {
    float inv[4];
#pragma unroll
    for (int r = 0; r < 4; r++) inv[r] = 1.0f / lrow[mi][r];
#pragma unroll
    for (int ni = 0; ni < 4; ni++)
#pragma unroll
      for (int r = 0; r < 4; r++) {
        int i_loc = wave * 32 + mi * 16 + quad * 4 + r;
        int srow = it0 + i_loc;
        int d = ni * 16 + l15;
        ctx[((size_t)(b * SS + srow)) * DM + h * DK + d] = (bf16_t)(accO[mi][ni][r] * inv[r]);
      }
  }
}

// ---------------- output projection: out = ctx @ Wo (fp32 out) ----------------
__global__ __launch_bounds__(256) void k_gemm_out(const bf16_t* __restrict__ A,
                                                  const bf16_t* __restrict__ Wot,
                                                  float* __restrict__ out) {
  __shared__ bf16_t As[128 * LDP];
  __shared__ bf16_t Bs[128 * LDP];
  const int m0 = blockIdx.y * 128, n0 = blockIdx.x * 128;
  f32x4 acc[4][4];
  gemm_tile(A, Wot, DM, m0, n0, As, Bs, acc);

  const int tid = threadIdx.x;
  const int lane = tid & 63, wave = tid >> 6;
  const int l15 = lane & 15, quad = lane >> 4;
  const int wm = (wave >> 1) * 64, wn = (wave & 1) * 64;
#pragma unroll
  for (int i = 0; i < 4; i++)
#pragma unroll
    for (int j = 0; j < 4; j++)
#pragma unroll
      for (int r = 0; r < 4; r++) {
        int m = m0 + wm + i * 16 + quad * 4 + r;
        int n = n0 + wn + j * 16 + l15;
        out[(size_t)m * DM + n] = acc[i][j][r];
      }
}

extern "C" void kernel_launch(void* const* d_in, const int* in_sizes, int n_in,
                              void* d_out, int out_size, void* d_ws, size_t ws_size,
                              hipStream_t stream) {
  (void)in_sizes; (void)n_in; (void)out_size; (void)ws_size;
  const float* H  = (const float*)d_in[0];
  const float* Wq = (const float*)d_in[1];
  const float* Wk = (const float*)d_in[2];
  const float* Wv = (const float*)d_in[3];
  const float* Wo = (const float*)d_in[4];
  const float* rel = (const float*)d_in[5];
  float* out = (float*)d_out;

  char* w = (char*)d_ws;
  bf16_t* Hbf = (bf16_t*)w; w += (size_t)MM * DM * 2;
  bf16_t* Wqt = (bf16_t*)w; w += (size_t)DM * DM * 2;
  bf16_t* Wkt = (bf16_t*)w; w += (size_t)DM * DM * 2;
  bf16_t* Wvt = (bf16_t*)w; w += (size_t)DM * DM * 2;
  bf16_t* Wot = (bf16_t*)w; w += (size_t)DM * DM * 2;
  bf16_t* Q   = (bf16_t*)w; w += (size_t)MM * DM * 2;
  bf16_t* K   = (bf16_t*)w; w += (size_t)MM * DM * 2;
  bf16_t* Vt  = (bf16_t*)w; w += (size_t)MM * DM * 2;
  bf16_t* CTX = (bf16_t*)w; w += (size_t)MM * DM * 2;
  float* biasT = (float*)w;  // NH * 4095 floats

  k_convert<<<MM * DM / 4 / 256, 256, 0, stream>>>(H, Hbf, MM * DM / 4);
  k_transpose<<<dim3(16, 16, 4), 256, 0, stream>>>(Wq, Wk, Wv, Wo, Wqt, Wkt, Wvt, Wot);
  k_bias<<<(2 * SS - 1 + 255) / 256, 256, 0, stream>>>(rel, biasT);
  k_gemm_qkv<<<dim3(DM / 128, MM / 128, 3), 256, 0, stream>>>(Hbf, Wqt, Wkt, Wvt, Q, K, Vt);
  k_attn<<<dim3(SS / 128, NB * NH), 256, 0, stream>>>(Q, K, Vt, biasT, CTX);
  k_gemm_out<<<dim3(DM / 128, MM / 128), 256, 0, stream>>>(CTX, Wot, out);
}

// Round 2
// 430.944 us; speedup vs baseline: 1.2840x; 1.2840x over previous
//
#include <hip/hip_runtime.h>

typedef __bf16 bf16_t;
typedef __bf16 bf16x4 __attribute__((ext_vector_type(4)));
typedef __bf16 bf16x8 __attribute__((ext_vector_type(8)));
typedef float f32x4 __attribute__((ext_vector_type(4)));

#define NB 4        // batch
#define SS 2048     // seq
#define DM 1024     // d_model
#define NH 16       // heads
#define DK 64       // d_kv
#define MM (NB*SS)  // 8192 rows
#define LOG2E 1.44269504f

// ---------------- convert H (fp32) -> bf16 ----------------
__global__ __launch_bounds__(256) void k_convert(const float* __restrict__ in,
                                                 bf16_t* __restrict__ out, int n4) {
  int i = blockIdx.x * 256 + threadIdx.x;
  if (i < n4) {
    float4 v = ((const float4*)in)[i];
    bf16x4 o = {(bf16_t)v.x, (bf16_t)v.y, (bf16_t)v.z, (bf16_t)v.w};
    *(bf16x4*)(out + 4 * (size_t)i) = o;
  }
}

// ---------------- transpose-convert weights: Wt[n][k] = bf16(W[k][n]) ----------------
__global__ __launch_bounds__(256) void k_transpose(
    const float* __restrict__ W0, const float* __restrict__ W1,
    const float* __restrict__ W2, const float* __restrict__ W3,
    bf16_t* __restrict__ T0, bf16_t* __restrict__ T1,
    bf16_t* __restrict__ T2, bf16_t* __restrict__ T3) {
  __shared__ float t[64][65];
  const float* W = blockIdx.z == 0 ? W0 : blockIdx.z == 1 ? W1 : blockIdx.z == 2 ? W2 : W3;
  bf16_t* T = blockIdx.z == 0 ? T0 : blockIdx.z == 1 ? T1 : blockIdx.z == 2 ? T2 : T3;
  int k0 = blockIdx.y * 64, n0 = blockIdx.x * 64;
  int tid = threadIdx.x;
#pragma unroll
  for (int i = 0; i < 16; i++) {
    int idx = tid + i * 256; int r = idx >> 6, c = idx & 63;
    t[r][c] = W[(size_t)(k0 + r) * DM + n0 + c];
  }
  __syncthreads();
#pragma unroll
  for (int i = 0; i < 16; i++) {
    int idx = tid + i * 256; int r = idx >> 6, c = idx & 63;
    T[(size_t)(n0 + r) * DM + k0 + c] = (bf16_t)t[c][r];
  }
}

// ---------------- T5 bias table, pre-scaled by log2(e): biasT[h][rel+2047] ----------------
__global__ __launch_bounds__(256) void k_bias(const float* __restrict__ rel_emb,
                                              float* __restrict__ biasT) {
  int t = blockIdx.x * 256 + threadIdx.x;
  if (t >= 2 * SS - 1) return;
  int rel = t - (SS - 1);      // rel = j - i (memory - context)
  int n = -rel;                // reference: n = -relative_position
  int ret = 0;
  if (n < 0) { ret = 16; n = -n; }
  int bucket;
  if (n < 8) bucket = n;
  else {
    int v = 8 + (int)(logf((float)n * 0.125f) * (8.0f / logf(16.0f)));
    bucket = v < 15 ? v : 15;
  }
  bucket += ret;
#pragma unroll
  for (int h = 0; h < NH; h++)
    biasT[h * (2 * SS - 1) + t] = rel_emb[bucket * NH + h] * LOG2E;
}

// ---------------- async 16B global -> LDS ----------------
__device__ __forceinline__ void gld16(const bf16_t* g, bf16_t* l) {
  __builtin_amdgcn_global_load_lds(
      (const __attribute__((address_space(1))) unsigned int*)g,
      (__attribute__((address_space(3))) unsigned int*)l, 16, 0, 0);
}

// ---------------- m97-style GEMM mainloop: C[128x128] = A[MxK] * Bt[NxK]^T ----------------
// Unpadded LDS [128][32] bf16; staging via global_load_lds dwordx4 (lane i -> base + i*16B).
__device__ __forceinline__ void gemm_tile(const bf16_t* __restrict__ A,
                                          const bf16_t* __restrict__ Bt, const int K,
                                          const int m0, const int n0,
                                          bf16_t* As, bf16_t* Bs, f32x4 (&acc)[4][4]) {
  const int tid = threadIdx.x;
  const int lane = tid & 63, wave = tid >> 6;
  const int l15 = lane & 15, quad = lane >> 4;
  const int wm = (wave >> 1) * 64, wn = (wave & 1) * 64;
  const int wwu = __builtin_amdgcn_readfirstlane(wave);  // provably wave-uniform LDS base
  const f32x4 z4 = {0.f, 0.f, 0.f, 0.f};
#pragma unroll
  for (int i = 0; i < 4; i++)
#pragma unroll
    for (int j = 0; j < 4; j++) acc[i][j] = z4;

  const int rr = lane >> 2;         // 0..15 row within 16-row chunk
  const int cc = (lane & 3) * 8;    // elem col 0,8,16,24
  for (int k0 = 0; k0 < K; k0 += 32) {
    __syncthreads();
    // wave w stages rows [32w,32w+32) of both tiles; lane deposits at chunkbase+lane*16B
    gld16(A + (size_t)(m0 + wwu * 32 + rr) * K + k0 + cc,       As + wwu * 1024);
    gld16(A + (size_t)(m0 + wwu * 32 + 16 + rr) * K + k0 + cc,  As + wwu * 1024 + 512);
    gld16(Bt + (size_t)(n0 + wwu * 32 + rr) * K + k0 + cc,      Bs + wwu * 1024);
    gld16(Bt + (size_t)(n0 + wwu * 32 + 16 + rr) * K + k0 + cc, Bs + wwu * 1024 + 512);
    __syncthreads();  // drains vmcnt (global_load_lds) before consuming
    bf16x8 af[4], bfr[4];
#pragma unroll
    for (int i = 0; i < 4; i++) {
      af[i]  = *(const bf16x8*)(As + (wm + i * 16 + l15) * 32 + quad * 8);
      bfr[i] = *(const bf16x8*)(Bs + (wn + i * 16 + l15) * 32 + quad * 8);
    }
#pragma unroll
    for (int i = 0; i < 4; i++)
#pragma unroll
      for (int j = 0; j < 4; j++)
        acc[i][j] = __builtin_amdgcn_mfma_f32_16x16x32_bf16(af[i], bfr[j], acc[i][j], 0, 0, 0);
  }
}

// ---------------- QKV projection: Q scaled by log2e; Q,K [bh][s][d], V^T [bh][d][s] ----------
__global__ __launch_bounds__(256) void k_gemm_qkv(
    const bf16_t* __restrict__ A, const bf16_t* __restrict__ Wqt,
    const bf16_t* __restrict__ Wkt, const bf16_t* __restrict__ Wvt,
    bf16_t* __restrict__ Q, bf16_t* __restrict__ Ko, bf16_t* __restrict__ Vt) {
  __shared__ bf16_t As[128 * 32];
  __shared__ bf16_t Bs[128 * 32];
  const int which = blockIdx.z;
  const bf16_t* Bt = which == 0 ? Wqt : (which == 1 ? Wkt : Wvt);
  const int m0 = blockIdx.y * 128, n0 = blockIdx.x * 128;
  f32x4 acc[4][4];
  gemm_tile(A, Bt, DM, m0, n0, As, Bs, acc);

  const int tid = threadIdx.x;
  const int lane = tid & 63, wave = tid >> 6;
  const int l15 = lane & 15, quad = lane >> 4;
  const int wm = (wave >> 1) * 64, wn = (wave & 1) * 64;

  if (which < 2) {
    bf16_t* dst = which == 0 ? Q : Ko;
    const float qs = which == 0 ? LOG2E : 1.0f;  // fold log2e into Q for exp2-softmax
#pragma unroll
    for (int i = 0; i < 4; i++)
#pragma unroll
      for (int j = 0; j < 4; j++)
#pragma unroll
        for (int r = 0; r < 4; r++) {
          int m = m0 + wm + i * 16 + quad * 4 + r;
          int n = n0 + wn + j * 16 + l15;
          int b = m >> 11, s = m & (SS - 1);
          int h = n >> 6, d = n & 63;
          dst[(((size_t)(b * NH + h)) * SS + s) * DK + d] = (bf16_t)(acc[i][j][r] * qs);
        }
  } else {
#pragma unroll
    for (int i = 0; i < 4; i++)
#pragma unroll
      for (int j = 0; j < 4; j++) {
        int m = m0 + wm + i * 16 + quad * 4;   // 4 consecutive s
        int n = n0 + wn + j * 16 + l15;
        int b = m >> 11, s = m & (SS - 1);
        int h = n >> 6, d = n & 63;
        bf16x4 pk = {(bf16_t)acc[i][j][0], (bf16_t)acc[i][j][1],
                     (bf16_t)acc[i][j][2], (bf16_t)acc[i][j][3]};
        *(bf16x4*)(&Vt[(((size_t)(b * NH + h)) * DK + d) * SS + s]) = pk;
      }
  }
}

// ---------------- flash attention, no-max softmax (T5 logits fit fp32: max ~e^50) ---------
// Barrier-free K-loop: K/V/Q fragments direct from global; Ps rows are wave-private.
__global__ __launch_bounds__(256, 4) void k_attn(const bf16_t* __restrict__ Qg,
                                                 const bf16_t* __restrict__ Kg,
                                                 const bf16_t* __restrict__ Vt,
                                                 const float* __restrict__ biasT,
                                                 bf16_t* __restrict__ ctx) {
  const int bh = blockIdx.y;
  const int b = bh >> 4, h = bh & 15;
  const int it0 = blockIdx.x * 128;
  const bf16_t* Qp = Qg + ((size_t)bh * SS + it0) * DK;
  const bf16_t* Kp = Kg + (size_t)bh * SS * DK;
  const bf16_t* Vp = Vt + (size_t)bh * DK * SS;
  const float* biasH = biasT + h * (2 * SS - 1);

  __shared__ bf16_t Ps[128][40];      // P round-trip (D-layout -> A-layout); wave-private rows
  __shared__ float bias_l[2176];      // bias window for this q-block: idx = j - i_loc + 127

  const int tid = threadIdx.x;
  const int lane = tid & 63, wave = tid >> 6;
  const int l15 = lane & 15, quad = lane >> 4;

  // stage bias window once (only barrier in the kernel)
#pragma unroll
  for (int t = tid; t < 2176; t += 256) {
    int g = t - it0 + 1920;                    // = (j - i_loc) + 2047
    g = g < 0 ? 0 : (g > 4094 ? 4094 : g);
    bias_l[t] = biasH[g];
  }

  // Q fragments direct from global (rows wave*32+mi*16+l15, 16 full cache lines/instr)
  bf16x8 qf0[2], qf1[2];
#pragma unroll
  for (int mi = 0; mi < 2; mi++) {
    int row = wave * 32 + mi * 16 + l15;
    qf0[mi] = *(const bf16x8*)(Qp + (size_t)row * DK + quad * 8);
    qf1[mi] = *(const bf16x8*)(Qp + (size_t)row * DK + 32 + quad * 8);
  }

  float lsum[2][4];
  f32x4 accO[2][4];
  const f32x4 z4 = {0.f, 0.f, 0.f, 0.f};
#pragma unroll
  for (int mi = 0; mi < 2; mi++)
#pragma unroll
    for (int r = 0; r < 4; r++) lsum[mi][r] = 0.f;
#pragma unroll
  for (int mi = 0; mi < 2; mi++)
#pragma unroll
    for (int ni = 0; ni < 4; ni++) accO[mi][ni] = z4;

  __syncthreads();  // bias_l ready

  for (int j0 = 0; j0 < SS; j0 += 32) {
    asm volatile("" ::: "memory");  // iteration boundary: keep prev Ps reads before next writes

    // K fragments: B[n=key][k=d], rows j0+ji*16+l15, 16 full lines per instr
    bf16x8 kf0[2], kf1[2], vf[4];
#pragma unroll
    for (int ji = 0; ji < 2; ji++) {
      const bf16_t* kr = Kp + (size_t)(j0 + ji * 16 + l15) * DK;
      kf0[ji] = *(const bf16x8*)(kr + quad * 8);
      kf1[ji] = *(const bf16x8*)(kr + 32 + quad * 8);
    }
    // V^T fragments: B[n=d][k=key], 64B contiguous per row
#pragma unroll
    for (int ni = 0; ni < 4; ni++)
      vf[ni] = *(const bf16x8*)(Vp + (size_t)(ni * 16 + l15) * SS + j0 + quad * 8);

    // scores (pre-scaled by log2e via Q)
    f32x4 sc[2][2];
#pragma unroll
    for (int mi = 0; mi < 2; mi++)
#pragma unroll
      for (int ji = 0; ji < 2; ji++) {
        f32x4 t = __builtin_amdgcn_mfma_f32_16x16x32_bf16(qf0[mi], kf0[ji], z4, 0, 0, 0);
        sc[mi][ji] = __builtin_amdgcn_mfma_f32_16x16x32_bf16(qf1[mi], kf1[ji], t, 0, 0, 0);
      }

    // softmax numerator, no max subtraction, no shuffles; per-lane partial row sums
#pragma unroll
    for (int mi = 0; mi < 2; mi++) {
      const int ibase = j0 + l15 - wave * 32 - mi * 16 - quad * 4 + 127;
      const int il0 = wave * 32 + mi * 16 + quad * 4;
#pragma unroll
      for (int r = 0; r < 4; r++) {
        float s0 = sc[mi][0][r] + bias_l[ibase - r];
        float s1 = sc[mi][1][r] + bias_l[ibase - r + 16];
        float p0 = exp2f(s0);
        float p1 = exp2f(s1);
        lsum[mi][r] += p0 + p1;
        Ps[il0 + r][l15] = (bf16_t)p0;
        Ps[il0 + r][16 + l15] = (bf16_t)p1;
      }
    }

    // wave-private LDS RAW: DS pipe is in-order per wave; wait + compiler barrier
    asm volatile("s_waitcnt lgkmcnt(0)" ::: "memory");

    // PV: P as A-operand, V^T as B-operand
    bf16x8 pf[2];
#pragma unroll
    for (int mi = 0; mi < 2; mi++)
      pf[mi] = *(const bf16x8*)(&Ps[wave * 32 + mi * 16 + l15][quad * 8]);
#pragma unroll
    for (int mi = 0; mi < 2; mi++)
#pragma unroll
      for (int ni = 0; ni < 4; ni++)
        accO[mi][ni] = __builtin_amdgcn_mfma_f32_16x16x32_bf16(pf[mi], vf[ni], accO[mi][ni], 0, 0, 0);
  }

  // one final row-sum reduction across the 16 lanes sharing each row
#pragma unroll
  for (int mi = 0; mi < 2; mi++) {
    float inv[4];
#pragma unroll
    for (int r = 0; r < 4; r++) {
      float l = lsum[mi][r];
      l += __shfl_xor(l, 1);
      l += __shfl_xor(l, 2);
      l += __shfl_xor(l, 4);
      l += __shfl_xor(l, 8);
      inv[r] = 1.0f / l;
    }
#pragma unroll
    for (int ni = 0; ni < 4; ni++)
#pragma unroll
      for (int r = 0; r < 4; r++) {
        int i_loc = wave * 32 + mi * 16 + quad * 4 + r;
        int srow = it0 + i_loc;
        int d = ni * 16 + l15;
        ctx[((size_t)(b * SS + srow)) * DM + h * DK + d] = (bf16_t)(accO[mi][ni][r] * inv[r]);
      }
  }
}

// ---------------- output projection: out = ctx @ Wo (fp32 out) ----------------
__global__ __launch_bounds__(256) void k_gemm_out(const bf16_t* __restrict__ A,
                                                  const bf16_t* __restrict__ Wot,
                                                  float* __restrict__ out) {
  __shared__ bf16_t As[128 * 32];
  __shared__ bf16_t Bs[128 * 32];
  const int m0 = blockIdx.y * 128, n0 = blockIdx.x * 128;
  f32x4 acc[4][4];
  gemm_tile(A, Wot, DM, m0, n0, As, Bs, acc);

  const int tid = threadIdx.x;
  const int lane = tid & 63, wave = tid >> 6;
  const int l15 = lane & 15, quad = lane >> 4;
  const int wm = (wave >> 1) * 64, wn = (wave & 1) * 64;
#pragma unroll
  for (int i = 0; i < 4; i++)
#pragma unroll
    for (int j = 0; j < 4; j++)
#pragma unroll
      for (int r = 0; r < 4; r++) {
        int m = m0 + wm + i * 16 + quad * 4 + r;
        int n = n0 + wn + j * 16 + l15;
        out[(size_t)m * DM + n] = acc[i][j][r];
      }
}

extern "C" void kernel_launch(void* const* d_in, const int* in_sizes, int n_in,
                              void* d_out, int out_size, void* d_ws, size_t ws_size,
                              hipStream_t stream) {
  (void)in_sizes; (void)n_in; (void)out_size; (void)ws_size;
  const float* H  = (const float*)d_in[0];
  const float* Wq = (const float*)d_in[1];
  const float* Wk = (const float*)d_in[2];
  const float* Wv = (const float*)d_in[3];
  const float* Wo = (const float*)d_in[4];
  const float* rel = (const float*)d_in[5];
  float* out = (float*)d_out;

  char* w = (char*)d_ws;
  bf16_t* Hbf = (bf16_t*)w; w += (size_t)MM * DM * 2;
  bf16_t* Wqt = (bf16_t*)w; w += (size_t)DM * DM * 2;
  bf16_t* Wkt = (bf16_t*)w; w += (size_t)DM * DM * 2;
  bf16_t* Wvt = (bf16_t*)w; w += (size_t)DM * DM * 2;
  bf16_t* Wot = (bf16_t*)w; w += (size_t)DM * DM * 2;
  bf16_t* Q   = (bf16_t*)w; w += (size_t)MM * DM * 2;
  bf16_t* K   = (bf16_t*)w; w += (size_t)MM * DM * 2;
  bf16_t* Vt  = (bf16_t*)w; w += (size_t)MM * DM * 2;
  bf16_t* CTX = (bf16_t*)w; w += (size_t)MM * DM * 2;
  float* biasT = (float*)w;  // NH * 4095 floats

  k_convert<<<MM * DM / 4 / 256, 256, 0, stream>>>(H, Hbf, MM * DM / 4);
  k_transpose<<<dim3(16, 16, 4), 256, 0, stream>>>(Wq, Wk, Wv, Wo, Wqt, Wkt, Wvt, Wot);
  k_bias<<<(2 * SS - 1 + 255) / 256, 256, 0, stream>>>(rel, biasT);
  k_gemm_qkv<<<dim3(DM / 128, MM / 128, 3), 256, 0, stream>>>(Hbf, Wqt, Wkt, Wvt, Q, K, Vt);
  k_attn<<<dim3(SS / 128, NB * NH), 256, 0, stream>>>(Q, K, Vt, biasT, CTX);
  k_gemm_out<<<dim3(DM / 128, MM / 128), 256, 0, stream>>>(CTX, Wot, out);
}

// Round 3
// 429.456 us; speedup vs baseline: 1.2885x; 1.0035x over previous
//
#include <hip/hip_runtime.h>

typedef __bf16 bf16_t;
typedef __bf16 bf16x4 __attribute__((ext_vector_type(4)));
typedef __bf16 bf16x8 __attribute__((ext_vector_type(8)));
typedef float f32x4 __attribute__((ext_vector_type(4)));

#define NB 4        // batch
#define SS 2048     // seq
#define DM 1024     // d_model
#define NH 16       // heads
#define DK 64       // d_kv
#define MM (NB*SS)  // 8192 rows
#define LOG2E 1.44269504f

// ---------------- convert H (fp32) -> bf16 ----------------
__global__ __launch_bounds__(256) void k_convert(const float* __restrict__ in,
                                                 bf16_t* __restrict__ out, int n4) {
  int i = blockIdx.x * 256 + threadIdx.x;
  if (i < n4) {
    float4 v = ((const float4*)in)[i];
    bf16x4 o = {(bf16_t)v.x, (bf16_t)v.y, (bf16_t)v.z, (bf16_t)v.w};
    *(bf16x4*)(out + 4 * (size_t)i) = o;
  }
}

// ---------------- transpose-convert weights: Wt[n][k] = bf16(W[k][n]) ----------------
__global__ __launch_bounds__(256) void k_transpose(
    const float* __restrict__ W0, const float* __restrict__ W1,
    const float* __restrict__ W2, const float* __restrict__ W3,
    bf16_t* __restrict__ T0, bf16_t* __restrict__ T1,
    bf16_t* __restrict__ T2, bf16_t* __restrict__ T3) {
  __shared__ float t[64][65];
  const float* W = blockIdx.z == 0 ? W0 : blockIdx.z == 1 ? W1 : blockIdx.z == 2 ? W2 : W3;
  bf16_t* T = blockIdx.z == 0 ? T0 : blockIdx.z == 1 ? T1 : blockIdx.z == 2 ? T2 : T3;
  int k0 = blockIdx.y * 64, n0 = blockIdx.x * 64;
  int tid = threadIdx.x;
#pragma unroll
  for (int i = 0; i < 16; i++) {
    int idx = tid + i * 256; int r = idx >> 6, c = idx & 63;
    t[r][c] = W[(size_t)(k0 + r) * DM + n0 + c];
  }
  __syncthreads();
#pragma unroll
  for (int i = 0; i < 16; i++) {
    int idx = tid + i * 256; int r = idx >> 6, c = idx & 63;
    T[(size_t)(n0 + r) * DM + k0 + c] = (bf16_t)t[c][r];
  }
}

// ---------------- T5 bias table, pre-scaled by log2(e): biasT[h][rel+2047] ----------------
__global__ __launch_bounds__(256) void k_bias(const float* __restrict__ rel_emb,
                                              float* __restrict__ biasT) {
  int t = blockIdx.x * 256 + threadIdx.x;
  if (t >= 2 * SS - 1) return;
  int rel = t - (SS - 1);      // rel = j - i (memory - context)
  int n = -rel;                // reference: n = -relative_position
  int ret = 0;
  if (n < 0) { ret = 16; n = -n; }
  int bucket;
  if (n < 8) bucket = n;
  else {
    int v = 8 + (int)(logf((float)n * 0.125f) * (8.0f / logf(16.0f)));
    bucket = v < 15 ? v : 15;
  }
  bucket += ret;
#pragma unroll
  for (int h = 0; h < NH; h++)
    biasT[h * (2 * SS - 1) + t] = rel_emb[bucket * NH + h] * LOG2E;
}

// ---------------- async 16B global -> LDS ----------------
__device__ __forceinline__ void gld16(const bf16_t* g, bf16_t* l) {
  __builtin_amdgcn_global_load_lds(
      (const __attribute__((address_space(1))) unsigned int*)g,
      (__attribute__((address_space(3))) unsigned int*)l, 16, 0, 0);
}

// ---------------- m97-style GEMM mainloop: C[128x128] = A[MxK] * Bt[NxK]^T ----------------
__device__ __forceinline__ void gemm_tile(const bf16_t* __restrict__ A,
                                          const bf16_t* __restrict__ Bt, const int K,
                                          const int m0, const int n0,
                                          bf16_t* As, bf16_t* Bs, f32x4 (&acc)[4][4]) {
  const int tid = threadIdx.x;
  const int lane = tid & 63, wave = tid >> 6;
  const int l15 = lane & 15, quad = lane >> 4;
  const int wm = (wave >> 1) * 64, wn = (wave & 1) * 64;
  const int wwu = __builtin_amdgcn_readfirstlane(wave);
  const f32x4 z4 = {0.f, 0.f, 0.f, 0.f};
#pragma unroll
  for (int i = 0; i < 4; i++)
#pragma unroll
    for (int j = 0; j < 4; j++) acc[i][j] = z4;

  const int rr = lane >> 2;
  const int cc = (lane & 3) * 8;
  for (int k0 = 0; k0 < K; k0 += 32) {
    __syncthreads();
    gld16(A + (size_t)(m0 + wwu * 32 + rr) * K + k0 + cc,       As + wwu * 1024);
    gld16(A + (size_t)(m0 + wwu * 32 + 16 + rr) * K + k0 + cc,  As + wwu * 1024 + 512);
    gld16(Bt + (size_t)(n0 + wwu * 32 + rr) * K + k0 + cc,      Bs + wwu * 1024);
    gld16(Bt + (size_t)(n0 + wwu * 32 + 16 + rr) * K + k0 + cc, Bs + wwu * 1024 + 512);
    __syncthreads();
    bf16x8 af[4], bfr[4];
#pragma unroll
    for (int i = 0; i < 4; i++) {
      af[i]  = *(const bf16x8*)(As + (wm + i * 16 + l15) * 32 + quad * 8);
      bfr[i] = *(const bf16x8*)(Bs + (wn + i * 16 + l15) * 32 + quad * 8);
    }
#pragma unroll
    for (int i = 0; i < 4; i++)
#pragma unroll
      for (int j = 0; j < 4; j++)
        acc[i][j] = __builtin_amdgcn_mfma_f32_16x16x32_bf16(af[i], bfr[j], acc[i][j], 0, 0, 0);
  }
}

// ---------------- QKV projection: Q scaled by log2e; Q,K [bh][s][d], V^T [bh][d][s] ----------
__global__ __launch_bounds__(256) void k_gemm_qkv(
    const bf16_t* __restrict__ A, const bf16_t* __restrict__ Wqt,
    const bf16_t* __restrict__ Wkt, const bf16_t* __restrict__ Wvt,
    bf16_t* __restrict__ Q, bf16_t* __restrict__ Ko, bf16_t* __restrict__ Vt) {
  __shared__ bf16_t As[128 * 32];
  __shared__ bf16_t Bs[128 * 32];
  const int which = blockIdx.z;
  const bf16_t* Bt = which == 0 ? Wqt : (which == 1 ? Wkt : Wvt);
  const int m0 = blockIdx.y * 128, n0 = blockIdx.x * 128;
  f32x4 acc[4][4];
  gemm_tile(A, Bt, DM, m0, n0, As, Bs, acc);

  const int tid = threadIdx.x;
  const int lane = tid & 63, wave = tid >> 6;
  const int l15 = lane & 15, quad = lane >> 4;
  const int wm = (wave >> 1) * 64, wn = (wave & 1) * 64;

  if (which < 2) {
    bf16_t* dst = which == 0 ? Q : Ko;
    const float qs = which == 0 ? LOG2E : 1.0f;
#pragma unroll
    for (int i = 0; i < 4; i++)
#pragma unroll
      for (int j = 0; j < 4; j++)
#pragma unroll
        for (int r = 0; r < 4; r++) {
          int m = m0 + wm + i * 16 + quad * 4 + r;
          int n = n0 + wn + j * 16 + l15;
          int b = m >> 11, s = m & (SS - 1);
          int h = n >> 6, d = n & 63;
          dst[(((size_t)(b * NH + h)) * SS + s) * DK + d] = (bf16_t)(acc[i][j][r] * qs);
        }
  } else {
#pragma unroll
    for (int i = 0; i < 4; i++)
#pragma unroll
      for (int j = 0; j < 4; j++) {
        int m = m0 + wm + i * 16 + quad * 4;
        int n = n0 + wn + j * 16 + l15;
        int b = m >> 11, s = m & (SS - 1);
        int h = n >> 6, d = n & 63;
        bf16x4 pk = {(bf16_t)acc[i][j][0], (bf16_t)acc[i][j][1],
                     (bf16_t)acc[i][j][2], (bf16_t)acc[i][j][3]};
        *(bf16x4*)(&Vt[(((size_t)(b * NH + h)) * DK + d) * SS + s]) = pk;
      }
  }
}

// ---------------- flash attention, S^T form with key-permuted fragments -------------------
// Scores computed transposed: S^T = mfma(K_perm, Q). Key permutation perm_t(l15) =
// 8*(l15>>2) + (l15&3) + 4*t puts exp2(S^T)'s D-fragment exactly into the B-operand
// layout needed for O^T = mfma(V^T, P^T) -- no LDS round-trip, no shuffles, no barriers.
__global__ __launch_bounds__(256, 3) void k_attn(const bf16_t* __restrict__ Qg,
                                                 const bf16_t* __restrict__ Kg,
                                                 const bf16_t* __restrict__ Vt,
                                                 const float* __restrict__ biasT,
                                                 bf16_t* __restrict__ ctx) {
  const int bh = blockIdx.y;
  const int b = bh >> 4, h = bh & 15;
  const int it0 = blockIdx.x * 128;
  const bf16_t* Qp = Qg + ((size_t)bh * SS + it0) * DK;
  const bf16_t* Kp = Kg + (size_t)bh * SS * DK;
  const bf16_t* Vp = Vt + (size_t)bh * DK * SS;
  const float* biasH = biasT + h * (2 * SS - 1);

  // float4-replicated bias window: bias4[u][k] = bias(j - i) at u = j - i + it0 + 127, k=r
  __shared__ f32x4 bias4[2175];

  const int tid = threadIdx.x;
  const int lane = tid & 63, wave = tid >> 6;
  const int l15 = lane & 15, quad = lane >> 4;

  for (int u = tid; u < 2175; u += 256) {
    f32x4 v;
#pragma unroll
    for (int k = 0; k < 4; k++) {
      int g = u + k - it0 - 127 + (SS - 1);
      g = g < 0 ? 0 : (g > 2 * SS - 2 ? 2 * SS - 2 : g);
      v[k] = biasH[g];
    }
    bias4[u] = v;
  }

  // Q fragments (B-operand): lane l15 = qrow-local, k = d = quad*8+j (+32 for hi half)
  bf16x8 qf_lo[2], qf_hi[2];
#pragma unroll
  for (int mi = 0; mi < 2; mi++) {
    const bf16_t* qr = Qp + (size_t)(wave * 32 + mi * 16 + l15) * DK;
    qf_lo[mi] = *(const bf16x8*)(qr + quad * 8);
    qf_hi[mi] = *(const bf16x8*)(qr + 32 + quad * 8);
  }

  // K fragment loader (A-operand, permuted rows): tile t lane row = perm_t(l15)
  const int kprow = 8 * (l15 >> 2) + (l15 & 3);
  auto load_kf = [&](int j0, bf16x8* kf) {
    const bf16_t* k0 = Kp + (size_t)(j0 + kprow) * DK;
    kf[0] = *(const bf16x8*)(k0 + quad * 8);         // tile0, d 0-31
    kf[1] = *(const bf16x8*)(k0 + 32 + quad * 8);    // tile0, d 32-63
    const bf16_t* k1 = k0 + 4 * DK;
    kf[2] = *(const bf16x8*)(k1 + quad * 8);         // tile1, d 0-31
    kf[3] = *(const bf16x8*)(k1 + 32 + quad * 8);    // tile1, d 32-63
  };

  float lsum[2] = {0.f, 0.f};
  f32x4 accO[2][4];
  const f32x4 z4 = {0.f, 0.f, 0.f, 0.f};
#pragma unroll
  for (int mi = 0; mi < 2; mi++)
#pragma unroll
    for (int ni = 0; ni < 4; ni++) accO[mi][ni] = z4;

  bf16x8 kfA[4], kfB[4];
  load_kf(0, kfA);

  __syncthreads();  // bias4 ready (only barrier in kernel)

  for (int j0 = 0; j0 < SS; j0 += 32) {
    // V^T fragments for this iter (consumed at the end -> natural prefetch distance)
    bf16x8 vf[4];
#pragma unroll
    for (int ni = 0; ni < 4; ni++)
      vf[ni] = *(const bf16x8*)(Vp + (size_t)(ni * 16 + l15) * SS + j0 + quad * 8);
    // K fragments for next iter (register double-buffer; last-iter overrun lands in Vt, unused)
    load_kf(j0 + 32, kfB);

    // bias vectors: u0 = j - i + it0 + 127 at r=0
    f32x4 bsv[2][2];
#pragma unroll
    for (int mi = 0; mi < 2; mi++) {
      int ub = j0 + 8 * quad - wave * 32 - mi * 16 - l15 + 127;
      bsv[mi][0] = bias4[ub];
      bsv[mi][1] = bias4[ub + 4];
    }

    // S^T = K_perm . Q^T : D[m=key_perm][n=qrow]
    f32x4 sc[2][2];
#pragma unroll
    for (int mi = 0; mi < 2; mi++)
#pragma unroll
      for (int t = 0; t < 2; t++) {
        f32x4 x = __builtin_amdgcn_mfma_f32_16x16x32_bf16(kfA[2 * t], qf_lo[mi], z4, 0, 0, 0);
        sc[mi][t] = __builtin_amdgcn_mfma_f32_16x16x32_bf16(kfA[2 * t + 1], qf_hi[mi], x, 0, 0, 0);
      }

    // exp2 softmax numerator; D-frag (keys 8q+r / 8q+4+r) == B-operand frag (keys quad*8+j)
#pragma unroll
    for (int mi = 0; mi < 2; mi++) {
      f32x4 s0 = sc[mi][0] + bsv[mi][0];
      f32x4 s1 = sc[mi][1] + bsv[mi][1];
      f32x4 p0, p1;
#pragma unroll
      for (int r = 0; r < 4; r++) { p0[r] = exp2f(s0[r]); p1[r] = exp2f(s1[r]); }
      lsum[mi] += (p0[0] + p0[1] + p0[2] + p0[3]) + (p1[0] + p1[1] + p1[2] + p1[3]);
      bf16x8 pf = {(bf16_t)p0[0], (bf16_t)p0[1], (bf16_t)p0[2], (bf16_t)p0[3],
                   (bf16_t)p1[0], (bf16_t)p1[1], (bf16_t)p1[2], (bf16_t)p1[3]};
      // O^T += V^T . P^T : D[m=d][n=qrow]
#pragma unroll
      for (int ni = 0; ni < 4; ni++)
        accO[mi][ni] = __builtin_amdgcn_mfma_f32_16x16x32_bf16(vf[ni], pf, accO[mi][ni], 0, 0, 0);
    }

#pragma unroll
    for (int f = 0; f < 4; f++) kfA[f] = kfB[f];
  }

  // row sums: lane holds partial over its keys for qrow l15; combine quads via xor 16/32
#pragma unroll
  for (int mi = 0; mi < 2; mi++) {
    float l = lsum[mi];
    l += __shfl_xor(l, 16);
    l += __shfl_xor(l, 32);
    float inv = 1.0f / l;
    int srow = it0 + wave * 32 + mi * 16 + l15;
#pragma unroll
    for (int ni = 0; ni < 4; ni++) {
      bf16x4 pk = {(bf16_t)(accO[mi][ni][0] * inv), (bf16_t)(accO[mi][ni][1] * inv),
                   (bf16_t)(accO[mi][ni][2] * inv), (bf16_t)(accO[mi][ni][3] * inv)};
      *(bf16x4*)(&ctx[((size_t)(b * SS + srow)) * DM + h * DK + ni * 16 + quad * 4]) = pk;
    }
  }
}

// ---------------- output projection: out = ctx @ Wo (fp32 out) ----------------
__global__ __launch_bounds__(256) void k_gemm_out(const bf16_t* __restrict__ A,
                                                  const bf16_t* __restrict__ Wot,
                                                  float* __restrict__ out) {
  __shared__ bf16_t As[128 * 32];
  __shared__ bf16_t Bs[128 * 32];
  const int m0 = blockIdx.y * 128, n0 = blockIdx.x * 128;
  f32x4 acc[4][4];
  gemm_tile(A, Wot, DM, m0, n0, As, Bs, acc);

  const int tid = threadIdx.x;
  const int lane = tid & 63, wave = tid >> 6;
  const int l15 = lane & 15, quad = lane >> 4;
  const int wm = (wave >> 1) * 64, wn = (wave & 1) * 64;
#pragma unroll
  for (int i = 0; i < 4; i++)
#pragma unroll
    for (int j = 0; j < 4; j++)
#pragma unroll
      for (int r = 0; r < 4; r++) {
        int m = m0 + wm + i * 16 + quad * 4 + r;
        int n = n0 + wn + j * 16 + l15;
        out[(size_t)m * DM + n] = acc[i][j][r];
      }
}

extern "C" void kernel_launch(void* const* d_in, const int* in_sizes, int n_in,
                              void* d_out, int out_size, void* d_ws, size_t ws_size,
                              hipStream_t stream) {
  (void)in_sizes; (void)n_in; (void)out_size; (void)ws_size;
  const float* H  = (const float*)d_in[0];
  const float* Wq = (const float*)d_in[1];
  const float* Wk = (const float*)d_in[2];
  const float* Wv = (const float*)d_in[3];
  const float* Wo = (const float*)d_in[4];
  const float* rel = (const float*)d_in[5];
  float* out = (float*)d_out;

  char* w = (char*)d_ws;
  bf16_t* Hbf = (bf16_t*)w; w += (size_t)MM * DM * 2;
  bf16_t* Wqt = (bf16_t*)w; w += (size_t)DM * DM * 2;
  bf16_t* Wkt = (bf16_t*)w; w += (size_t)DM * DM * 2;
  bf16_t* Wvt = (bf16_t*)w; w += (size_t)DM * DM * 2;
  bf16_t* Wot = (bf16_t*)w; w += (size_t)DM * DM * 2;
  bf16_t* Q   = (bf16_t*)w; w += (size_t)MM * DM * 2;
  bf16_t* K   = (bf16_t*)w; w += (size_t)MM * DM * 2;  // k_attn prefetch may overrun 4KB into Vt (harmless)
  bf16_t* Vt  = (bf16_t*)w; w += (size_t)MM * DM * 2;
  bf16_t* CTX = (bf16_t*)w; w += (size_t)MM * DM * 2;
  float* biasT = (float*)w;  // NH * 4095 floats

  k_convert<<<MM * DM / 4 / 256, 256, 0, stream>>>(H, Hbf, MM * DM / 4);
  k_transpose<<<dim3(16, 16, 4), 256, 0, stream>>>(Wq, Wk, Wv, Wo, Wqt, Wkt, Wvt, Wot);
  k_bias<<<(2 * SS - 1 + 255) / 256, 256, 0, stream>>>(rel, biasT);
  k_gemm_qkv<<<dim3(DM / 128, MM / 128, 3), 256, 0, stream>>>(Hbf, Wqt, Wkt, Wvt, Q, K, Vt);
  k_attn<<<dim3(SS / 128, NB * NH), 256, 0, stream>>>(Q, K, Vt, biasT, CTX);
  k_gemm_out<<<dim3(DM / 128, MM / 128), 256, 0, stream>>>(CTX, Wot, out);
}

// Round 4
// 312.158 us; speedup vs baseline: 1.7726x; 1.3758x over previous
//
#include <hip/hip_runtime.h>

typedef __bf16 bf16_t;
typedef __bf16 bf16x4 __attribute__((ext_vector_type(4)));
typedef __bf16 bf16x8 __attribute__((ext_vector_type(8)));
typedef float f32x4 __attribute__((ext_vector_type(4)));

#define NB 4        // batch
#define SS 2048     // seq
#define DM 1024     // d_model
#define NH 16       // heads
#define DK 64       // d_kv
#define MM (NB*SS)  // 8192 rows
#define LOG2E 1.44269504f

// ---------------- convert H (fp32) -> bf16 ----------------
__global__ __launch_bounds__(256) void k_convert(const float* __restrict__ in,
                                                 bf16_t* __restrict__ out, int n4) {
  int i = blockIdx.x * 256 + threadIdx.x;
  if (i < n4) {
    float4 v = ((const float4*)in)[i];
    bf16x4 o = {(bf16_t)v.x, (bf16_t)v.y, (bf16_t)v.z, (bf16_t)v.w};
    *(bf16x4*)(out + 4 * (size_t)i) = o;
  }
}

// ---------------- transpose-convert weights: Wt[n][k] = bf16(W[k][n]) ----------------
__global__ __launch_bounds__(256) void k_transpose(
    const float* __restrict__ W0, const float* __restrict__ W1,
    const float* __restrict__ W2, const float* __restrict__ W3,
    bf16_t* __restrict__ T0, bf16_t* __restrict__ T1,
    bf16_t* __restrict__ T2, bf16_t* __restrict__ T3) {
  __shared__ float t[64][65];
  const float* W = blockIdx.z == 0 ? W0 : blockIdx.z == 1 ? W1 : blockIdx.z == 2 ? W2 : W3;
  bf16_t* T = blockIdx.z == 0 ? T0 : blockIdx.z == 1 ? T1 : blockIdx.z == 2 ? T2 : T3;
  int k0 = blockIdx.y * 64, n0 = blockIdx.x * 64;
  int tid = threadIdx.x;
#pragma unroll
  for (int i = 0; i < 16; i++) {
    int idx = tid + i * 256; int r = idx >> 6, c = idx & 63;
    t[r][c] = W[(size_t)(k0 + r) * DM + n0 + c];
  }
  __syncthreads();
#pragma unroll
  for (int i = 0; i < 16; i++) {
    int idx = tid + i * 256; int r = idx >> 6, c = idx & 63;
    T[(size_t)(n0 + r) * DM + k0 + c] = (bf16_t)t[c][r];
  }
}

// ---------------- T5 bias table, pre-scaled by log2(e): biasT[h][rel+2047] ----------------
__global__ __launch_bounds__(256) void k_bias(const float* __restrict__ rel_emb,
                                              float* __restrict__ biasT) {
  int t = blockIdx.x * 256 + threadIdx.x;
  if (t >= 2 * SS - 1) return;
  int rel = t - (SS - 1);      // rel = j - i (memory - context)
  int n = -rel;                // reference: n = -relative_position
  int ret = 0;
  if (n < 0) { ret = 16; n = -n; }
  int bucket;
  if (n < 8) bucket = n;
  else {
    int v = 8 + (int)(logf((float)n * 0.125f) * (8.0f / logf(16.0f)));
    bucket = v < 15 ? v : 15;
  }
  bucket += ret;
#pragma unroll
  for (int h = 0; h < NH; h++)
    biasT[h * (2 * SS - 1) + t] = rel_emb[bucket * NH + h] * LOG2E;
}

// ---------------- async 16B global -> LDS (lane i deposits at lds_base + 16*i) -------------
__device__ __forceinline__ void gld16(const bf16_t* g, bf16_t* l) {
  __builtin_amdgcn_global_load_lds(
      (const __attribute__((address_space(1))) unsigned int*)g,
      (__attribute__((address_space(3))) unsigned int*)l, 16, 0, 0);
}

// ---------------- m97-style GEMM mainloop: C[128x128] = A[MxK] * Bt[NxK]^T ----------------
__device__ __forceinline__ void gemm_tile(const bf16_t* __restrict__ A,
                                          const bf16_t* __restrict__ Bt, const int K,
                                          const int m0, const int n0,
                                          bf16_t* As, bf16_t* Bs, f32x4 (&acc)[4][4]) {
  const int tid = threadIdx.x;
  const int lane = tid & 63, wave = tid >> 6;
  const int l15 = lane & 15, quad = lane >> 4;
  const int wm = (wave >> 1) * 64, wn = (wave & 1) * 64;
  const int wwu = __builtin_amdgcn_readfirstlane(wave);
  const f32x4 z4 = {0.f, 0.f, 0.f, 0.f};
#pragma unroll
  for (int i = 0; i < 4; i++)
#pragma unroll
    for (int j = 0; j < 4; j++) acc[i][j] = z4;

  const int rr = lane >> 2;
  const int cc = (lane & 3) * 8;
  for (int k0 = 0; k0 < K; k0 += 32) {
    __syncthreads();
    gld16(A + (size_t)(m0 + wwu * 32 + rr) * K + k0 + cc,       As + wwu * 1024);
    gld16(A + (size_t)(m0 + wwu * 32 + 16 + rr) * K + k0 + cc,  As + wwu * 1024 + 512);
    gld16(Bt + (size_t)(n0 + wwu * 32 + rr) * K + k0 + cc,      Bs + wwu * 1024);
    gld16(Bt + (size_t)(n0 + wwu * 32 + 16 + rr) * K + k0 + cc, Bs + wwu * 1024 + 512);
    __syncthreads();
    bf16x8 af[4], bfr[4];
#pragma unroll
    for (int i = 0; i < 4; i++) {
      af[i]  = *(const bf16x8*)(As + (wm + i * 16 + l15) * 32 + quad * 8);
      bfr[i] = *(const bf16x8*)(Bs + (wn + i * 16 + l15) * 32 + quad * 8);
    }
#pragma unroll
    for (int i = 0; i < 4; i++)
#pragma unroll
      for (int j = 0; j < 4; j++)
        acc[i][j] = __builtin_amdgcn_mfma_f32_16x16x32_bf16(af[i], bfr[j], acc[i][j], 0, 0, 0);
  }
}

// ---------------- QKV projection: Q scaled by log2e; Q,K [bh][s][d]; V panel-tiled ----------
// V layout: Vt[bh][panel=s/32][d][s%32]  -> a 32-key V^T tile is one contiguous 8KB block.
__global__ __launch_bounds__(256) void k_gemm_qkv(
    const bf16_t* __restrict__ A, const bf16_t* __restrict__ Wqt,
    const bf16_t* __restrict__ Wkt, const bf16_t* __restrict__ Wvt,
    bf16_t* __restrict__ Q, bf16_t* __restrict__ Ko, bf16_t* __restrict__ Vt) {
  __shared__ bf16_t As[128 * 32];
  __shared__ bf16_t Bs[128 * 32];
  const int which = blockIdx.z;
  const bf16_t* Bt = which == 0 ? Wqt : (which == 1 ? Wkt : Wvt);
  const int m0 = blockIdx.y * 128, n0 = blockIdx.x * 128;
  f32x4 acc[4][4];
  gemm_tile(A, Bt, DM, m0, n0, As, Bs, acc);

  const int tid = threadIdx.x;
  const int lane = tid & 63, wave = tid >> 6;
  const int l15 = lane & 15, quad = lane >> 4;
  const int wm = (wave >> 1) * 64, wn = (wave & 1) * 64;

  if (which < 2) {
    bf16_t* dst = which == 0 ? Q : Ko;
    const float qs = which == 0 ? LOG2E : 1.0f;
#pragma unroll
    for (int i = 0; i < 4; i++)
#pragma unroll
      for (int j = 0; j < 4; j++)
#pragma unroll
        for (int r = 0; r < 4; r++) {
          int m = m0 + wm + i * 16 + quad * 4 + r;
          int n = n0 + wn + j * 16 + l15;
          int b = m >> 11, s = m & (SS - 1);
          int h = n >> 6, d = n & 63;
          dst[(((size_t)(b * NH + h)) * SS + s) * DK + d] = (bf16_t)(acc[i][j][r] * qs);
        }
  } else {
#pragma unroll
    for (int i = 0; i < 4; i++)
#pragma unroll
      for (int j = 0; j < 4; j++) {
        int m = m0 + wm + i * 16 + quad * 4;   // 4 consecutive s (4-aligned, same 32-panel)
        int n = n0 + wn + j * 16 + l15;
        int b = m >> 11, s = m & (SS - 1);
        int h = n >> 6, d = n & 63;
        int p = s >> 5, off = s & 31;
        bf16x4 pk = {(bf16_t)acc[i][j][0], (bf16_t)acc[i][j][1],
                     (bf16_t)acc[i][j][2], (bf16_t)acc[i][j][3]};
        *(bf16x4*)(&Vt[(((size_t)((b * NH + h) * 64 + p)) * DK + d) * 32 + off]) = pk;
      }
  }
}

// ---------------- flash attention: LDS-staged, fragment-major, wave-specialized 2x2 --------
// Block: 128 q-rows x one (b,h); j-loop over 32 tiles of 64 keys, double-buffered LDS,
// ONE barrier per iter (stage next buffer right after barrier -> full-iteration latency).
// Wave w = (qh=w>>1, kh=w&1): 64 q-rows x 32 keys; no redundant LDS reads across waves.
// S^T = mfma(K_perm, Q, BIAS_Cfrag); exp2; P^T feeds PV directly; sums via ones-MFMA.
__global__ __launch_bounds__(256, 2) void k_attn(const bf16_t* __restrict__ Qg,
                                                 const bf16_t* __restrict__ Kg,
                                                 const bf16_t* __restrict__ Vt,
                                                 const float* __restrict__ biasT,
                                                 bf16_t* __restrict__ ctx) {
  const int bh = blockIdx.y;
  const int b = bh >> 4, h = bh & 15;
  const int it0 = blockIdx.x * 128;
  const bf16_t* Qp = Qg + ((size_t)bh * SS + it0) * DK;
  const bf16_t* Kp = Kg + (size_t)bh * SS * DK;
  const bf16_t* VtP = Vt + (size_t)bh * 64 * DK * 32;  // [panel][d][32]
  const float* biasH = biasT + h * (2 * SS - 1);

  // KV[buf][0]=K slots (t,h): t=16-key subtile, h=d-half; KV[buf][1]=V slots (c,ni).
  // Each slot is fragment-major: lane i's 16B at +16*i. Reused as fp32 O-reduce buffer.
  __shared__ bf16_t KV[2][2][8][512];     // 32 KB
  __shared__ float bias2a[2175][2];       // x2-replicated bias window, 17.4 KB
  __shared__ float OsumS[2][4][16];       // per (qh, mi, qrow) partial denominators

  const int tid = threadIdx.x;
  const int lane = tid & 63, wave = tid >> 6;
  const int l15 = lane & 15, quad = lane >> 4;
  const int kh = wave & 1, qh = wave >> 1;
  const int kperm = 8 * (l15 >> 2) + (l15 & 3);

  // bias window fill: bias2a[u] = {B(u), B(u+1)}, B(u)=biasH[clamp(u - it0 - 127 + 2047)]
  for (int u = tid; u < 2175; u += 256) {
    int g0 = u - it0 + 1920;       // u - it0 - 127 + 2047
    int g1 = g0 + 1;
    g0 = g0 < 0 ? 0 : (g0 > 2 * SS - 2 ? 2 * SS - 2 : g0);
    g1 = g1 < 0 ? 0 : (g1 > 2 * SS - 2 ? 2 * SS - 2 : g1);
    bias2a[u][0] = biasH[g0];
    bias2a[u][1] = biasH[g1];
  }

  // stage one 64-key tile into buffer `buf` (16 gld16 split 4-per-wave)
  auto stage = [&](int buf, int j0) {
    {  // K: wave covers subtile t=wave, both halves. Global rows permuted to fragment order.
      int t = wave;
      const bf16_t* g = Kp + (size_t)(j0 + 32 * (t >> 1) + 4 * (t & 1) + kperm) * DK + quad * 8;
      gld16(g,      &KV[buf][0][t * 2 + 0][0]);
      gld16(g + 32, &KV[buf][0][t * 2 + 1][0]);
    }
    {  // V: wave covers chunk c=wave>>1, ni pair. Panels are contiguous 8KB.
      int c = wave >> 1, nib = (wave & 1) * 2;
      const bf16_t* g = VtP + ((size_t)((j0 >> 5) + c) * DK + nib * 16 + l15) * 32 + quad * 8;
      gld16(g,           &KV[buf][1][c * 4 + nib][0]);
      gld16(g + 16 * 32, &KV[buf][1][c * 4 + nib + 1][0]);
    }
  };

  // Q fragments (persistent): qrows 64*qh + mi*16 + l15
  bf16x8 qf[4][2];
#pragma unroll
  for (int mi = 0; mi < 4; mi++) {
    const bf16_t* qr = Qp + (size_t)(64 * qh + mi * 16 + l15) * DK + quad * 8;
    qf[mi][0] = *(const bf16x8*)qr;
    qf[mi][1] = *(const bf16x8*)(qr + 32);
  }

  f32x4 accO[4][4], accS[4];
  const f32x4 z4 = {0.f, 0.f, 0.f, 0.f};
#pragma unroll
  for (int mi = 0; mi < 4; mi++) {
    accS[mi] = z4;
#pragma unroll
    for (int ni = 0; ni < 4; ni++) accO[mi][ni] = z4;
  }
  const bf16_t one = (bf16_t)1.0f;
  const bf16x8 ones = {one, one, one, one, one, one, one, one};

  stage(0, 0);
  const int ub0 = 32 * kh - 64 * qh + 8 * quad - l15 + 127;  // bias frag base (wave-invariant)

  for (int it = 0; it < 32; ++it) {
    const int cb = it & 1;
    __syncthreads();                       // drains prev staging (vmcnt) + orders buffers
    if (it < 31) stage(cb ^ 1, (it + 1) * 64);

    // fragment loads: lane-linear ds_read_b128, conflict-free
    bf16x8 kf[2][2], vf[4];
#pragma unroll
    for (int t = 0; t < 2; t++)
#pragma unroll
      for (int hf = 0; hf < 2; hf++)
        kf[t][hf] = *(const bf16x8*)&KV[cb][0][(2 * kh + t) * 2 + hf][lane * 8];
#pragma unroll
    for (int ni = 0; ni < 4; ni++)
      vf[ni] = *(const bf16x8*)&KV[cb][1][kh * 4 + ni][lane * 8];

    const int jb = it * 64 + ub0;
#pragma unroll
    for (int mi = 0; mi < 4; mi++) {
      // bias C-fragment: keys consecutive in reg r (perm0(q*4+r)=8q+r)
      const int ub = jb - mi * 16;
      float2 a0 = *(const float2*)bias2a[ub],     b0 = *(const float2*)bias2a[ub + 2];
      float2 a1 = *(const float2*)bias2a[ub + 4], b1 = *(const float2*)bias2a[ub + 6];
      f32x4 c0 = {a0.x, a0.y, b0.x, b0.y};
      f32x4 c1 = {a1.x, a1.y, b1.x, b1.y};
      // S^T tiles (bias pre-added via C operand)
      f32x4 s0 = __builtin_amdgcn_mfma_f32_16x16x32_bf16(
          kf[0][1], qf[mi][1],
          __builtin_amdgcn_mfma_f32_16x16x32_bf16(kf[0][0], qf[mi][0], c0, 0, 0, 0), 0, 0, 0);
      f32x4 s1 = __builtin_amdgcn_mfma_f32_16x16x32_bf16(
          kf[1][1], qf[mi][1],
          __builtin_amdgcn_mfma_f32_16x16x32_bf16(kf[1][0], qf[mi][0], c1, 0, 0, 0), 0, 0, 0);
      // exp2 numerator -> P^T B-fragment (keys q*8+j: j=r from t0, j=4+r from t1)
      bf16x8 pf = {(bf16_t)exp2f(s0[0]), (bf16_t)exp2f(s0[1]),
                   (bf16_t)exp2f(s0[2]), (bf16_t)exp2f(s0[3]),
                   (bf16_t)exp2f(s1[0]), (bf16_t)exp2f(s1[1]),
                   (bf16_t)exp2f(s1[2]), (bf16_t)exp2f(s1[3])};
      // PV + denominator (ones-MFMA)
#pragma unroll
      for (int ni = 0; ni < 4; ni++)
        accO[mi][ni] = __builtin_amdgcn_mfma_f32_16x16x32_bf16(vf[ni], pf, accO[mi][ni], 0, 0, 0);
      accS[mi] = __builtin_amdgcn_mfma_f32_16x16x32_bf16(ones, pf, accS[mi], 0, 0, 0);
    }
  }

  // cross-wave combine over key-halves (kh=1 dumps partials; kh=0 reduces + writes out)
  __syncthreads();
  f32x4* Ored = (f32x4*)&KV[0][0][0][0];  // 32 KB, staging done
  if (kh) {
#pragma unroll
    for (int mi = 0; mi < 4; mi++) {
#pragma unroll
      for (int ni = 0; ni < 4; ni++)
        Ored[((qh * 4 + mi) * 4 + ni) * 64 + lane] = accO[mi][ni];
      if (quad == 0) OsumS[qh][mi][l15] = accS[mi][0];
    }
  }
  __syncthreads();
  if (!kh) {
#pragma unroll
    for (int mi = 0; mi < 4; mi++) {
      float l = accS[mi][0] + OsumS[qh][mi][l15];
      float inv = 1.0f / l;
      int srow = it0 + 64 * qh + mi * 16 + l15;
#pragma unroll
      for (int ni = 0; ni < 4; ni++) {
        f32x4 o = accO[mi][ni] + Ored[((qh * 4 + mi) * 4 + ni) * 64 + lane];
        bf16x4 pk = {(bf16_t)(o[0] * inv), (bf16_t)(o[1] * inv),
                     (bf16_t)(o[2] * inv), (bf16_t)(o[3] * inv)};
        *(bf16x4*)(&ctx[((size_t)(b * SS + srow)) * DM + h * DK + ni * 16 + quad * 4]) = pk;
      }
    }
  }
}

// ---------------- output projection: out = ctx @ Wo (fp32 out) ----------------
__global__ __launch_bounds__(256) void k_gemm_out(const bf16_t* __restrict__ A,
                                                  const bf16_t* __restrict__ Wot,
                                                  float* __restrict__ out) {
  __shared__ bf16_t As[128 * 32];
  __shared__ bf16_t Bs[128 * 32];
  const int m0 = blockIdx.y * 128, n0 = blockIdx.x * 128;
  f32x4 acc[4][4];
  gemm_tile(A, Wot, DM, m0, n0, As, Bs, acc);

  const int tid = threadIdx.x;
  const int lane = tid & 63, wave = tid >> 6;
  const int l15 = lane & 15, quad = lane >> 4;
  const int wm = (wave >> 1) * 64, wn = (wave & 1) * 64;
#pragma unroll
  for (int i = 0; i < 4; i++)
#pragma unroll
    for (int j = 0; j < 4; j++)
#pragma unroll
      for (int r = 0; r < 4; r++) {
        int m = m0 + wm + i * 16 + quad * 4 + r;
        int n = n0 + wn + j * 16 + l15;
        out[(size_t)m * DM + n] = acc[i][j][r];
      }
}

extern "C" void kernel_launch(void* const* d_in, const int* in_sizes, int n_in,
                              void* d_out, int out_size, void* d_ws, size_t ws_size,
                              hipStream_t stream) {
  (void)in_sizes; (void)n_in; (void)out_size; (void)ws_size;
  const float* H  = (const float*)d_in[0];
  const float* Wq = (const float*)d_in[1];
  const float* Wk = (const float*)d_in[2];
  const float* Wv = (const float*)d_in[3];
  const float* Wo = (const float*)d_in[4];
  const float* rel = (const float*)d_in[5];
  float* out = (float*)d_out;

  char* w = (char*)d_ws;
  bf16_t* Hbf = (bf16_t*)w; w += (size_t)MM * DM * 2;
  bf16_t* Wqt = (bf16_t*)w; w += (size_t)DM * DM * 2;
  bf16_t* Wkt = (bf16_t*)w; w += (size_t)DM * DM * 2;
  bf16_t* Wvt = (bf16_t*)w; w += (size_t)DM * DM * 2;
  bf16_t* Wot = (bf16_t*)w; w += (size_t)DM * DM * 2;
  bf16_t* Q   = (bf16_t*)w; w += (size_t)MM * DM * 2;
  bf16_t* K   = (bf16_t*)w; w += (size_t)MM * DM * 2;
  bf16_t* Vt  = (bf16_t*)w; w += (size_t)MM * DM * 2;
  bf16_t* CTX = (bf16_t*)w; w += (size_t)MM * DM * 2;
  float* biasT = (float*)w;  // NH * 4095 floats

  k_convert<<<MM * DM / 4 / 256, 256, 0, stream>>>(H, Hbf, MM * DM / 4);
  k_transpose<<<dim3(16, 16, 4), 256, 0, stream>>>(Wq, Wk, Wv, Wo, Wqt, Wkt, Wvt, Wot);
  k_bias<<<(2 * SS - 1 + 255) / 256, 256, 0, stream>>>(rel, biasT);
  k_gemm_qkv<<<dim3(DM / 128, MM / 128, 3), 256, 0, stream>>>(Hbf, Wqt, Wkt, Wvt, Q, K, Vt);
  k_attn<<<dim3(SS / 128, NB * NH), 256, 0, stream>>>(Q, K, Vt, biasT, CTX);
  k_gemm_out<<<dim3(DM / 128, MM / 128), 256, 0, stream>>>(CTX, Wot, out);
}